// Round 7
// baseline (65.995 us; speedup 1.0000x reference)
//
#include <hip/hip_runtime.h>
#include <hip/hip_bf16.h>

typedef float f32x4 __attribute__((ext_vector_type(4)));
typedef __bf16 bf16x8 __attribute__((ext_vector_type(8)));
typedef __bf16 bf16x4 __attribute__((ext_vector_type(4)));

#define AS1 __attribute__((address_space(1)))
#define AS3 __attribute__((address_space(3)))

static constexpr int BB = 32;      // batch
static constexpr int DM = 2560;    // d_model
static constexpr int DI = 5120;    // d_inner
static constexpr int NS = 16;      // ssm state N
static constexpr int RK = 160;     // dt_rank
static constexpr int NJ = 192;     // dt_rank + 2N

__device__ __forceinline__ float sigmoidf_(float x) { return 1.f / (1.f + __expf(-x)); }
__device__ __forceinline__ float softplusf_(float x) {
    return (x > 15.f) ? x : log1pf(__expf(x));
}

__device__ __forceinline__ bf16x8 cvt8(f32x4 a, f32x4 b) {
    bf16x8 r;
    r[0] = (__bf16)a[0]; r[1] = (__bf16)a[1]; r[2] = (__bf16)a[2]; r[3] = (__bf16)a[3];
    r[4] = (__bf16)b[0]; r[5] = (__bf16)b[1]; r[6] = (__bf16)b[2]; r[7] = (__bf16)b[3];
    return r;
}

#define WAITN(N) do { asm volatile("s_waitcnt vmcnt(" #N ")" ::: "memory"); \
                      __builtin_amdgcn_sched_barrier(0); } while (0)

// ---------------------------------------------------------------------------
// Wave-private skinny GEMM: 1 wave per block (64 thr). Wave owns a 32d x 32b
// output tile; per kstep (BK=32) it stages W (fp32, 4KB, 4 instr) and X
// (bf16, 2KB, 2 instr) into its own 3-deep LDS ring via global_load_lds.
// NO barriers anywhere (no inter-wave sharing) -> no convoy. Counted
// vmcnt(6): two stages always in flight, 2-iteration latency slack.
// Swizzle: W slot(row,c) holds chunk c^(row&7); X slot holds c^((row>>1)&3)
// (pre-swizzled global source, lane-linear LDS dest; reads undo same XOR).
// Split-K partials to disjoint buffers; consumer reduces.
// ---------------------------------------------------------------------------
__global__ __launch_bounds__(64) void gemmw(
    const float* __restrict__ W0, float* __restrict__ C0,
    const float* __restrict__ W1, float* __restrict__ C1,
    const __bf16* __restrict__ Xh,
    int K, int ldc, int nm, int S, int ksteps, int cstride)
{
    __shared__ float  Wb[3][32 * 32];   // 4KB per buf
    __shared__ __bf16 Xb[3][32 * 32];   // 2KB per buf

    int bid = blockIdx.x;
    int m = bid % nm;
    int rest = bid / nm;
    int s = rest % S;
    int mat = rest / S;
    const float* W = mat ? W1 : W0;
    float* C = (mat ? C1 : C0) + (size_t)s * cstride;

    int d0 = m * 32;
    int k0 = s * (K / S);

    int l = threadIdx.x;        // 0..63 (one wave)

    // W staging: instr i covers rows 8i+(l>>3); chunk slot l&7 pre-swizzled
    int wrr = l >> 3;
    int wch = (l & 7) ^ (wrr & 7);
    const float* wp0 = W + (size_t)(d0 +  0 + wrr) * K + k0 + wch * 4;
    const float* wp1 = W + (size_t)(d0 +  8 + wrr) * K + k0 + wch * 4;
    const float* wp2 = W + (size_t)(d0 + 16 + wrr) * K + k0 + wch * 4;
    const float* wp3 = W + (size_t)(d0 + 24 + wrr) * K + k0 + wch * 4;
    // X staging: instr i covers rows 16i+(l>>2); chunk slot l&3 pre-swizzled
    int xr  = l >> 2;
    int xc0 = (l & 3) ^ ((xr >> 1) & 3);
    int xc1 = (l & 3) ^ (((16 + xr) >> 1) & 3);
    const __bf16* xp0 = Xh + (size_t)(xr) * K + k0 + xc0 * 8;
    const __bf16* xp1 = Xh + (size_t)(16 + xr) * K + k0 + xc1 * 8;

#define STG(buf) do {                                                                    \
        __builtin_amdgcn_global_load_lds((const AS1 void*)wp0, (AS3 void*)&Wb[buf][ 0 * 32], 16, 0, 0); \
        __builtin_amdgcn_global_load_lds((const AS1 void*)wp1, (AS3 void*)&Wb[buf][ 8 * 32], 16, 0, 0); \
        __builtin_amdgcn_global_load_lds((const AS1 void*)wp2, (AS3 void*)&Wb[buf][16 * 32], 16, 0, 0); \
        __builtin_amdgcn_global_load_lds((const AS1 void*)wp3, (AS3 void*)&Wb[buf][24 * 32], 16, 0, 0); \
        __builtin_amdgcn_global_load_lds((const AS1 void*)xp0, (AS3 void*)&Xb[buf][ 0 * 32], 16, 0, 0); \
        __builtin_amdgcn_global_load_lds((const AS1 void*)xp1, (AS3 void*)&Xb[buf][16 * 32], 16, 0, 0); \
        wp0 += 32; wp1 += 32; wp2 += 32; wp3 += 32; xp0 += 32; xp1 += 32;                \
    } while (0)

    // Fragment read offsets (loop-invariant)
    int r16 = l & 15;
    int j2 = (l >> 4) * 2;      // W chunk base (fp32 16B chunks)
    int jb = l >> 4;            // X chunk (bf16 16B chunks)
    int ar0 = r16, ar1 = 16 + r16;
    int a00 = ar0 * 32 + ((j2    ) ^ (ar0 & 7)) * 4;
    int a01 = ar0 * 32 + ((j2 + 1) ^ (ar0 & 7)) * 4;
    int a10 = ar1 * 32 + ((j2    ) ^ (ar1 & 7)) * 4;
    int a11 = ar1 * 32 + ((j2 + 1) ^ (ar1 & 7)) * 4;
    int b0  = ar0 * 32 + ((jb ^ ((ar0 >> 1) & 3))) * 8;
    int b1  = ar1 * 32 + ((jb ^ ((ar1 >> 1) & 3))) * 8;

    STG(0);
    STG(1);

    f32x4 acc00 = {0.f, 0.f, 0.f, 0.f}, acc01 = {0.f, 0.f, 0.f, 0.f};
    f32x4 acc10 = {0.f, 0.f, 0.f, 0.f}, acc11 = {0.f, 0.f, 0.f, 0.f};

    for (int it = 0; it < ksteps; ++it) {
        int c = it % 3;
        if (it < ksteps - 1) WAITN(6); else WAITN(0);

        f32x4 wa0 = *(const f32x4*)&Wb[c][a00];
        f32x4 wa1 = *(const f32x4*)&Wb[c][a01];
        f32x4 wb0 = *(const f32x4*)&Wb[c][a10];
        f32x4 wb1 = *(const f32x4*)&Wb[c][a11];
        bf16x8 B0 = *(const bf16x8*)&Xb[c][b0];
        bf16x8 B1 = *(const bf16x8*)&Xb[c][b1];

        bf16x8 A0 = cvt8(wa0, wa1);
        bf16x8 A1 = cvt8(wb0, wb1);
        acc00 = __builtin_amdgcn_mfma_f32_16x16x32_bf16(A0, B0, acc00, 0, 0, 0);
        acc01 = __builtin_amdgcn_mfma_f32_16x16x32_bf16(A0, B1, acc01, 0, 0, 0);
        acc10 = __builtin_amdgcn_mfma_f32_16x16x32_bf16(A1, B0, acc10, 0, 0, 0);
        acc11 = __builtin_amdgcn_mfma_f32_16x16x32_bf16(A1, B1, acc11, 0, 0, 0);

        if (it + 2 < ksteps) STG((it + 2) % 3);
    }
#undef STG

    // C/D: col(batch) = l&15 (B-side), row(d) = (l>>4)*4 + j (A-side)
    int q4 = (l >> 4) * 4;
    *(f32x4*)&C[(size_t)(r16     ) * ldc + d0      + q4] = acc00;   // m0,n0
    *(f32x4*)&C[(size_t)(16 + r16) * ldc + d0      + q4] = acc01;   // m0,n1
    *(f32x4*)&C[(size_t)(r16     ) * ldc + d0 + 16 + q4] = acc10;   // m1,n0
    *(f32x4*)&C[(size_t)(16 + r16) * ldc + d0 + 16 + q4] = acc11;   // m1,n1
}

// ---------------------------------------------------------------------------
// fp32 -> bf16 cast (for x).  n multiple of 1024; each thread 4 elems.
// ---------------------------------------------------------------------------
__global__ __launch_bounds__(256) void cvtx(
    const float* __restrict__ in, __bf16* __restrict__ out)
{
    int i = (blockIdx.x * 256 + threadIdx.x) * 4;
    f32x4 v = *(const f32x4*)&in[i];
    bf16x4 o;
    o[0] = (__bf16)v[0]; o[1] = (__bf16)v[1]; o[2] = (__bf16)v[2]; o[3] = (__bf16)v[3];
    *(bf16x4*)&out[i] = o;
}

// ---------------------------------------------------------------------------
// Small-tile barrier GEMM (proven; K2 only: output D=192).
// ---------------------------------------------------------------------------
__global__ __launch_bounds__(256) void gemm32(
    const float* __restrict__ W0, float* __restrict__ C0,
    const float* __restrict__ W1, float* __restrict__ C1,
    const float* __restrict__ X,
    int K, int ldc, int nm, int S, int ksteps, int cstride)
{
    __shared__ float Wb[2][32 * 64];
    __shared__ float Xb[2][32 * 64];

    int bid = blockIdx.x;
    int m = bid % nm;
    int rest = bid / nm;
    int s = rest % S;
    int mat = rest / S;
    const float* W = mat ? W1 : W0;
    float* C = (mat ? C1 : C0) + (size_t)s * cstride;

    int d0 = m * 32;
    int k0 = s * (K / S);

    int t  = threadIdx.x;
    int l  = t & 63;
    int wv = t >> 6;
    int lr = l >> 4;
    int lc = l & 15;

    int row0 = 8 * wv + lr;
    int row1 = row0 + 4;
    int ch0 = lc ^ (row0 & 7);
    int ch1 = lc ^ (row1 & 7);
    const float* ws0 = W + (size_t)(d0 + row0) * K + k0 + ch0 * 4;
    const float* ws1 = W + (size_t)(d0 + row1) * K + k0 + ch1 * 4;
    const float* xs0 = X + (size_t)row0 * K + k0 + ch0 * 4;
    const float* xs1 = X + (size_t)row1 * K + k0 + ch1 * 4;
    int R0 = 8 * wv * 64;
    int R1 = (8 * wv + 4) * 64;

#define STAGE(pb)  do {                                                              \
        __builtin_amdgcn_global_load_lds((const AS1 void*)ws0, (AS3 void*)&Wb[pb][R0], 16, 0, 0); \
        __builtin_amdgcn_global_load_lds((const AS1 void*)ws1, (AS3 void*)&Wb[pb][R1], 16, 0, 0); \
        __builtin_amdgcn_global_load_lds((const AS1 void*)xs0, (AS3 void*)&Xb[pb][R0], 16, 0, 0); \
        __builtin_amdgcn_global_load_lds((const AS1 void*)xs1, (AS3 void*)&Xb[pb][R1], 16, 0, 0); \
        ws0 += 64; ws1 += 64; xs0 += 64; xs1 += 64;                                  \
    } while (0)

    int mh = wv & 1, nh = wv >> 1;
    int r16 = l & 15;
    int arow = mh * 16 + r16;
    int brow = nh * 16 + r16;
    int c0 = (l >> 4) * 2;
    int wo0 = arow * 64 + ((c0    ) ^ (arow & 7)) * 4;
    int wo1 = arow * 64 + ((c0 + 1) ^ (arow & 7)) * 4;
    int wo2 = arow * 64 + ((c0 + 8) ^ (arow & 7)) * 4;
    int wo3 = arow * 64 + ((c0 + 9) ^ (arow & 7)) * 4;
    int xo0 = brow * 64 + ((c0    ) ^ (brow & 7)) * 4;
    int xo1 = brow * 64 + ((c0 + 1) ^ (brow & 7)) * 4;
    int xo2 = brow * 64 + ((c0 + 8) ^ (brow & 7)) * 4;
    int xo3 = brow * 64 + ((c0 + 9) ^ (brow & 7)) * 4;

    STAGE(0);
    STAGE(1);

    f32x4 acc = {0.f, 0.f, 0.f, 0.f};

    for (int it = 0; it < ksteps; ++it) {
        int c = it & 1;
        if (it < ksteps - 1) WAITN(4); else WAITN(0);
        __builtin_amdgcn_s_barrier();

        f32x4 a0 = *(const f32x4*)&Wb[c][wo0];
        f32x4 a1 = *(const f32x4*)&Wb[c][wo1];
        f32x4 a2 = *(const f32x4*)&Wb[c][wo2];
        f32x4 a3 = *(const f32x4*)&Wb[c][wo3];
        f32x4 b0 = *(const f32x4*)&Xb[c][xo0];
        f32x4 b1 = *(const f32x4*)&Xb[c][xo1];
        f32x4 b2 = *(const f32x4*)&Xb[c][xo2];
        f32x4 b3 = *(const f32x4*)&Xb[c][xo3];
        acc = __builtin_amdgcn_mfma_f32_16x16x32_bf16(cvt8(a0, a1), cvt8(b0, b1), acc, 0, 0, 0);
        acc = __builtin_amdgcn_mfma_f32_16x16x32_bf16(cvt8(a2, a3), cvt8(b2, b3), acc, 0, 0, 0);

        __builtin_amdgcn_s_barrier();
        if (it + 2 < ksteps) STAGE(c);
    }
#undef STAGE

    int b = brow;
    int dbase = d0 + mh * 16 + (l >> 4) * 4;
    *(f32x4*)&C[(size_t)b * ldc + dbase] = acc;
}

// ---------------------------------------------------------------------------
// Depthwise causal conv (k=4) + SiLU + reduce K1 split-K partials (S=8).
// ---------------------------------------------------------------------------
__global__ __launch_bounds__(256) void convk(
    const float* __restrict__ P_xs, const float* __restrict__ P_res,
    const float* __restrict__ conv_states,
    const float* __restrict__ conv_w, const float* __restrict__ conv_b,
    float* __restrict__ conv_bd, float* __restrict__ res_bd)
{
    const size_t BD = (size_t)BB * DI;
    int d = blockIdx.x * 256 + threadIdx.x;
    int b = blockIdx.y;
    size_t o = (size_t)b * DI + d;
    float xs = 0.f, rs = 0.f;
    #pragma unroll
    for (int j = 0; j < 8; ++j) {
        xs += P_xs[j * BD + o];
        rs += P_res[j * BD + o];
    }
    res_bd[o] = rs;
    float v = conv_states[(size_t)(1 * BB + b) * DI + d] * conv_w[0 * DI + d]
            + conv_states[(size_t)(2 * BB + b) * DI + d] * conv_w[1 * DI + d]
            + conv_states[(size_t)(3 * BB + b) * DI + d] * conv_w[2 * DI + d]
            + xs * conv_w[3 * DI + d] + conv_b[d];
    conv_bd[o] = v * sigmoidf_(v);
}

// ---------------------------------------------------------------------------
// Reduce K2 split-K partials.
// ---------------------------------------------------------------------------
__global__ __launch_bounds__(256) void redx(
    const float* __restrict__ p, float* __restrict__ o, int S)
{
    int i = blockIdx.x * 256 + threadIdx.x;
    float sum = 0.f;
    for (int s = 0; s < S; ++s) sum += p[(size_t)s * BB * NJ + i];
    o[i] = sum;
}

// ---------------------------------------------------------------------------
// Reduce K4 split-K partials (S=20) into d_out.
// ---------------------------------------------------------------------------
__global__ __launch_bounds__(256) void rout(
    const float* __restrict__ p, float* __restrict__ o)
{
    const int SZ = BB * DM;
    int i = blockIdx.x * 256 + threadIdx.x;
    float s = 0.f;
    #pragma unroll
    for (int j = 0; j < 20; ++j) s += p[(size_t)j * SZ + i];
    o[i] = s;
}

// ---------------------------------------------------------------------------
// Fused dt GEMV + softplus + SSM recurrence + D skip + SiLU gate -> g (bf16).
// Block = 256 thr = 8 d x 32 b.  Grid = DI/8 = 640.
// ---------------------------------------------------------------------------
__global__ __launch_bounds__(256) void ssmk2(
    const float* __restrict__ x_db, const float* __restrict__ W_dt,
    const float* __restrict__ dt_bias, const float* __restrict__ A_log,
    const float* __restrict__ Dv, const float* __restrict__ ssm_state,
    const float* __restrict__ conv_bd, const float* __restrict__ res_bd,
    __bf16* __restrict__ g_bh)
{
    __shared__ float Wdt_s[8][164];
    __shared__ float xdb_s[BB][196];
    __shared__ float Al_s[8][NS];

    int t = threadIdx.x;
    int d0 = blockIdx.x * 8;

    for (int f = t; f < 8 * RK; f += 256)
        Wdt_s[f / RK][f % RK] = W_dt[(size_t)d0 * RK + f];
    for (int f = t; f < BB * NJ; f += 256)
        xdb_s[f / NJ][f % NJ] = x_db[f];
    if (t < 8 * NS)
        Al_s[t / NS][t % NS] = A_log[(size_t)(d0 + t / NS) * NS + t % NS];
    __syncthreads();

    int b  = t & 31;
    int dl = t >> 5;
    int d  = d0 + dl;

    float acc = 0.f;
    #pragma unroll 8
    for (int k4 = 0; k4 < RK / 4; ++k4) {
        f32x4 wv = *(const f32x4*)&Wdt_s[dl][k4 * 4];
        f32x4 xv = *(const f32x4*)&xdb_s[b][k4 * 4];
        acc += wv[0] * xv[0] + wv[1] * xv[1] + wv[2] * xv[2] + wv[3] * xv[3];
    }
    float dt = softplusf_(acc + dt_bias[d]);

    size_t off = (size_t)b * DI + d;
    float cv = conv_bd[off];
    float rv = res_bd[off];
    float Dd = Dv[d];

    const f32x4* sp = (const f32x4*)(ssm_state + off * NS);
    float y = 0.f;
    #pragma unroll
    for (int q = 0; q < 4; ++q) {
        f32x4 sv = sp[q];
        #pragma unroll
        for (int j = 0; j < 4; ++j) {
            int n = q * 4 + j;
            float dA = __expf(-dt * __expf(Al_s[dl][n]));
            y += (sv[j] * dA + dt * xdb_s[b][RK + n] * cv) * xdb_s[b][RK + NS + n];
        }
    }
    y += Dd * cv;
    g_bh[off] = (__bf16)(y * (rv * sigmoidf_(rv)));
}

// ---------------------------------------------------------------------------

extern "C" void kernel_launch(void* const* d_in, const int* in_sizes, int n_in,
                              void* d_out, int out_size, void* d_ws, size_t ws_size,
                              hipStream_t stream)
{
    const float* x           = (const float*)d_in[0];
    const float* conv_states = (const float*)d_in[1];
    const float* conv_w      = (const float*)d_in[2];
    const float* conv_b      = (const float*)d_in[3];
    const float* W_ssm_in    = (const float*)d_in[4];
    const float* W_mlp       = (const float*)d_in[5];
    const float* W_out       = (const float*)d_in[6];
    const float* W_x_proj    = (const float*)d_in[7];
    const float* W_dt        = (const float*)d_in[8];
    const float* dt_bias     = (const float*)d_in[9];
    const float* A_log       = (const float*)d_in[10];
    const float* Dv          = (const float*)d_in[11];
    const float* ssm_state   = (const float*)d_in[12];

    float* out = (float*)d_out;
    float* ws  = (float*)d_ws;

    const size_t BD = (size_t)BB * DI;          // 163840
    const int S1 = 8;                           // K1 split-K (gemmw)
    const int S2 = 20;                          // K2 split-K (gemm32)
    const int S4 = 20;                          // K4 split-K (gemmw)

    float* P_res   = ws;                        // 8*BD
    float* P_xs    = ws + 8 * BD;               // 8*BD
    // after convk, P region is reused: outp (S4*BB*DM) then g (bf16)
    float*  outp   = ws;                                    // 20*81920 floats
    __bf16* g_bh   = (__bf16*)(ws + (size_t)S4 * BB * DM);  // BD bf16
    float* conv_bd = ws + 16 * BD;
    float* res_bd  = conv_bd + BD;
    float* x_db_p  = res_bd + BD;               // S2*6144
    float* x_db    = x_db_p + (size_t)S2 * BB * NJ;
    __bf16* x_bh   = (__bf16*)(x_db + BB * NJ); // BB*DM bf16

    // x -> bf16
    cvtx<<<dim3((BB * DM) / 1024), 256, 0, stream>>>(x, x_bh);

    // K1: res/xs partials (dual matrix): K=2560, S=8, BK=32 -> ksteps=10
    gemmw<<<dim3((DI / 32) * S1 * 2), 64, 0, stream>>>(
        W_mlp, P_res, W_ssm_in, P_xs, x_bh, DM, DI, DI / 32, S1, (DM / S1) / 32, (int)BD);

    // conv + silu + reduce K1 partials
    convk<<<dim3(DI / 256, BB), 256, 0, stream>>>(
        P_xs, P_res, conv_states, conv_w, conv_b, conv_bd, res_bd);

    // K2: x_db partials = conv @ W_x_proj.T  (K=5120, S=20, ksteps=4, BK=64)
    gemm32<<<dim3(6 * S2), 256, 0, stream>>>(
        W_x_proj, x_db_p, W_x_proj, x_db_p, conv_bd, DI, NJ, 6, S2, (DI / S2) / 64, BB * NJ);

    // reduce x_db partials
    redx<<<dim3((BB * NJ) / 256), 256, 0, stream>>>(x_db_p, x_db, S2);

    // fused dt + SSM + gate -> g (bf16)
    ssmk2<<<dim3(DI / 8), 256, 0, stream>>>(
        x_db, W_dt, dt_bias, A_log, Dv, ssm_state, conv_bd, res_bd, g_bh);

    // K4: out partials = g @ W_out.T  (K=5120, S=20, BK=32 -> ksteps=8)
    gemmw<<<dim3((DM / 32) * S4), 64, 0, stream>>>(
        W_out, outp, W_out, outp, g_bh, DI, DM, DM / 32, S4, (DI / S4) / 32, BB * DM);

    // final reduce into d_out
    rout<<<dim3((BB * DM) / 256), 256, 0, stream>>>(outp, out);
}